// Round 11
// baseline (185.788 us; speedup 1.0000x reference)
//
#include <hip/hip_runtime.h>

#define NE 100000   // edges
#define NN 50000    // nodes

typedef short short8 __attribute__((ext_vector_type(8)));
typedef float f32x4 __attribute__((ext_vector_type(4)));
typedef unsigned short ushort;
typedef unsigned int uint;

__device__ inline ushort f2bf(float f) {
    unsigned int u = __float_as_uint(f);
    u += 0x7FFFu + ((u >> 16) & 1u);
    return (ushort)(u >> 16);
}
__device__ inline float bf2f(ushort u) {
    return __uint_as_float((unsigned int)u << 16);
}

__device__ inline short8 pack_bf8(float4 a, float4 b) {
    short8 r;
    r[0] = (short)f2bf(a.x); r[1] = (short)f2bf(a.y);
    r[2] = (short)f2bf(a.z); r[3] = (short)f2bf(a.w);
    r[4] = (short)f2bf(b.x); r[5] = (short)f2bf(b.y);
    r[6] = (short)f2bf(b.z); r[7] = (short)f2bf(b.w);
    return r;
}

// ---------------------------------------------------------------------------
// Prep: pack both layers' QKV (72 frags) + Wo (8 frags) into bf16 fragment
// order: wf[((s*12+t)*64+lane)*8+j] = W[k=32s+(lane>>4)*8+j][n=16t+(lane&15)]
// ---------------------------------------------------------------------------
__device__ inline void pack_qkv_slot(int slot, const float* Wq, const float* Wk,
                                     const float* Wv, ushort* wf)
{
    int lane = slot & 63;
    int st = slot >> 6;
    int s = st / 12, t = st % 12;
    int n = t * 16 + (lane & 15);
    int kb = s * 32 + (lane >> 4) * 8;
    const float* w = (n < 64) ? Wq : (n < 128) ? Wk : Wv;
    int nn = n & 63;
    #pragma unroll
    for (int j = 0; j < 8; ++j)
        wf[(size_t)slot * 8 + j] = f2bf(w[(size_t)(kb + j) * 64 + nn]);
}

__device__ inline void pack_wo_slot(int slot, const float* Wo, ushort* wf)
{
    int lane = slot & 63;
    int st = slot >> 6;
    int s = st / 4, t = st % 4;
    int n = t * 16 + (lane & 15);
    int kb = s * 32 + (lane >> 4) * 8;
    #pragma unroll
    for (int j = 0; j < 8; ++j)
        wf[(size_t)slot * 8 + j] = f2bf(Wo[(size_t)(kb + j) * 64 + n]);
}

__global__ __launch_bounds__(256) void prep_all(
    const float* __restrict__ l1Wq, const float* __restrict__ l1Wk,
    const float* __restrict__ l1Wv, const float* __restrict__ l1Wo,
    const float* __restrict__ l2Wq, const float* __restrict__ l2Wk,
    const float* __restrict__ l2Wv, const float* __restrict__ l2Wo,
    ushort* __restrict__ wf1, ushort* __restrict__ wf2,
    ushort* __restrict__ wo1, ushort* __restrict__ wo2)
{
    int idx = blockIdx.x * 256 + threadIdx.x;
    if (idx < 4608)            pack_qkv_slot(idx,         l1Wq, l1Wk, l1Wv, wf1);
    else if (idx < 9216)       pack_qkv_slot(idx - 4608,  l2Wq, l2Wk, l2Wv, wf2);
    else if (idx < 9728)       pack_wo_slot (idx - 9216,  l1Wo, wo1);
    else if (idx < 10240)      pack_wo_slot (idx - 9728,  l2Wo, wo2);
}

#define MFMA_B16(a, b, c) c = __builtin_amdgcn_mfma_f32_16x16x32_bf16(a, b, c, 0, 0, 0)

// ---------------------------------------------------------------------------
// QKV GEMM — MLP-first. __launch_bounds__(256,2): VGPR cap 256 so ALL loads
// (4 idx + 24 float4 A + 18 B frags) can be in flight simultaneously.
// Wave = 32 rows x 48 cols (n-tiles 3w..3w+2). Single barrier. Coalesced
// stores via LDS transpose. Structure identical to verified round-8B.
// ---------------------------------------------------------------------------
#define LOADROW(pref, ptr) \
    float4 pref##_0 = *(const float4*)((ptr) + koff);        \
    float4 pref##_1 = *(const float4*)((ptr) + koff + 4);    \
    float4 pref##_2 = *(const float4*)((ptr) + 32 + koff);   \
    float4 pref##_3 = *(const float4*)((ptr) + 32 + koff + 4);

#define LOADB(s) \
    short8 B##s##_0 = *(const short8*)(wfb + (size_t)((s) * 12 + 3 * w) * 1024);        \
    short8 B##s##_1 = *(const short8*)(wfb + (size_t)((s) * 12 + 3 * w) * 1024 + 1024); \
    short8 B##s##_2 = *(const short8*)(wfb + (size_t)((s) * 12 + 3 * w) * 1024 + 2048);

#define MSTEP(s) \
    MFMA_B16(A0s##s, B##s##_0, d00); MFMA_B16(A0s##s, B##s##_1, d01); \
    MFMA_B16(A0s##s, B##s##_2, d02);                                  \
    MFMA_B16(A1s##s, B##s##_0, d10); MFMA_B16(A1s##s, B##s##_1, d11); \
    MFMA_B16(A1s##s, B##s##_2, d12);

#define DUMPB(dreg, T_lit, n_lit) do {                                         \
    ushort* p_ = ldso + ((T_lit) * 16 + kg * 4) * 200 + (3 * w + (n_lit)) * 16 + r; \
    p_[0]   = f2bf(dreg[0]); p_[200] = f2bf(dreg[1]);                          \
    p_[400] = f2bf(dreg[2]); p_[600] = f2bf(dreg[3]);                          \
} while (0)

__global__ __launch_bounds__(256, 2) void qkv_mfma(
    const float* __restrict__ ef, const float* __restrict__ nodef,
    const int* __restrict__ eidx, const ushort* __restrict__ wfrag,
    ushort* __restrict__ qo, ushort* __restrict__ ko, ushort* __restrict__ vo)
{
    __shared__ __align__(16) ushort ldso[32 * 200];   // 12.8 KB transpose tile

    const int tid = threadIdx.x;
    const int l   = tid & 63;
    const int w   = tid >> 6;
    const int r   = l & 15;
    const int kg  = l >> 4;
    const int e0  = blockIdx.x * 32;

    const int ea  = e0 + r;
    const int eb  = e0 + 16 + r;
    const int eac = (ea < NE) ? ea : NE - 1;
    const int ebc = (eb < NE) ? eb : NE - 1;
    const int koff = kg * 8;

    // ---- index loads (4 independent) ----
    const int sa = eidx[eac];
    const int da = eidx[NE + eac];
    const int sb = eidx[ebc];
    const int db = eidx[NE + ebc];

    // ---- ALL 24 A float4 loads into named regs (96 VGPR in flight) ----
    LOADROW(xa0, ef    + (size_t)eac * 64)
    LOADROW(xa1, nodef + (size_t)sa  * 64)
    LOADROW(xa2, nodef + (size_t)da  * 64)
    LOADROW(xb0, ef    + (size_t)ebc * 64)
    LOADROW(xb1, nodef + (size_t)sb  * 64)
    LOADROW(xb2, nodef + (size_t)db  * 64)

    // ---- ALL 18 B fragment loads (72 VGPR in flight) ----
    const char* wfb = (const char*)wfrag + (size_t)l * 16;
    LOADB(0) LOADB(1) LOADB(2) LOADB(3) LOADB(4) LOADB(5)

    // ---- pack A to bf16 (after loads are all issued) ----
    short8 A0s0 = pack_bf8(xa0_0, xa0_1);
    short8 A0s1 = pack_bf8(xa0_2, xa0_3);
    short8 A0s2 = pack_bf8(xa1_0, xa1_1);
    short8 A0s3 = pack_bf8(xa1_2, xa1_3);
    short8 A0s4 = pack_bf8(xa2_0, xa2_1);
    short8 A0s5 = pack_bf8(xa2_2, xa2_3);
    short8 A1s0 = pack_bf8(xb0_0, xb0_1);
    short8 A1s1 = pack_bf8(xb0_2, xb0_3);
    short8 A1s2 = pack_bf8(xb1_0, xb1_1);
    short8 A1s3 = pack_bf8(xb1_2, xb1_3);
    short8 A1s4 = pack_bf8(xb2_0, xb2_1);
    short8 A1s5 = pack_bf8(xb2_2, xb2_3);

    f32x4 d00 = (f32x4)(0.f), d01 = (f32x4)(0.f), d02 = (f32x4)(0.f);
    f32x4 d10 = (f32x4)(0.f), d11 = (f32x4)(0.f), d12 = (f32x4)(0.f);

    MSTEP(0) MSTEP(1) MSTEP(2) MSTEP(3) MSTEP(4) MSTEP(5)

    DUMPB(d00, 0, 0); DUMPB(d01, 0, 1); DUMPB(d02, 0, 2);
    DUMPB(d10, 1, 0); DUMPB(d11, 1, 1); DUMPB(d12, 1, 2);
    __syncthreads();   // all 4 waves contributed their 48-col slices

    // ---- coalesced store: thread = (row = tid>>3, seg = tid&7), 16 B ----
    const int row  = tid >> 3;
    const int seg  = tid & 7;
    const int grow = e0 + row;
    if (grow < NE) {
        const ushort* rp = ldso + row * 200;
        *(short8*)(qo + (size_t)grow * 64 + seg * 8) = *(const short8*)(rp +   0 + seg * 8);
        *(short8*)(ko + (size_t)grow * 64 + seg * 8) = *(const short8*)(rp +  64 + seg * 8);
        *(short8*)(vo + (size_t)grow * 64 + seg * 8) = *(const short8*)(rp + 128 + seg * 8);
    }
}

// ---------------------------------------------------------------------------
// Attention: one wave per dst edge. lane = half*32 + h*8 + dd.
// ---------------------------------------------------------------------------
__global__ __launch_bounds__(256) void attn_kernel(
    const ushort* __restrict__ q, const ushort* __restrict__ kbuf,
    const ushort* __restrict__ vbuf, const int* __restrict__ adj_src,
    ushort* __restrict__ ao)
{
    const int wid  = (blockIdx.x * 256 + threadIdx.x) >> 6;
    const int lane = threadIdx.x & 63;
    if (wid >= NE) return;
    const int e    = wid;
    const int half = lane >> 5;
    const int l32  = lane & 31;

    const int4 nb = *(const int4*)(adj_src + e * 8 + half * 4);
    const int nbr0 = nb.x, nbr1 = nb.y, nbr2 = nb.z, nbr3 = nb.w;

    ushort2 qu = *(const ushort2*)(q + (size_t)e * 64 + l32 * 2);
    const float q0 = bf2f(qu.x), q1 = bf2f(qu.y);

    ushort2 ku0 = *(const ushort2*)(kbuf + (size_t)nbr0 * 64 + l32 * 2);
    ushort2 ku1 = *(const ushort2*)(kbuf + (size_t)nbr1 * 64 + l32 * 2);
    ushort2 ku2 = *(const ushort2*)(kbuf + (size_t)nbr2 * 64 + l32 * 2);
    ushort2 ku3 = *(const ushort2*)(kbuf + (size_t)nbr3 * 64 + l32 * 2);
    ushort2 vu0 = *(const ushort2*)(vbuf + (size_t)nbr0 * 64 + l32 * 2);
    ushort2 vu1 = *(const ushort2*)(vbuf + (size_t)nbr1 * 64 + l32 * 2);
    ushort2 vu2 = *(const ushort2*)(vbuf + (size_t)nbr2 * 64 + l32 * 2);
    ushort2 vu3 = *(const ushort2*)(vbuf + (size_t)nbr3 * 64 + l32 * 2);

    float s0 = q0 * bf2f(ku0.x) + q1 * bf2f(ku0.y);
    float s1 = q0 * bf2f(ku1.x) + q1 * bf2f(ku1.y);
    float s2 = q0 * bf2f(ku2.x) + q1 * bf2f(ku2.y);
    float s3 = q0 * bf2f(ku3.x) + q1 * bf2f(ku3.y);
    s0 += __shfl_xor(s0, 1); s0 += __shfl_xor(s0, 2); s0 += __shfl_xor(s0, 4);
    s1 += __shfl_xor(s1, 1); s1 += __shfl_xor(s1, 2); s1 += __shfl_xor(s1, 4);
    s2 += __shfl_xor(s2, 1); s2 += __shfl_xor(s2, 2); s2 += __shfl_xor(s2, 4);
    s3 += __shfl_xor(s3, 1); s3 += __shfl_xor(s3, 2); s3 += __shfl_xor(s3, 4);
    s0 *= 0.25f; s1 *= 0.25f; s2 *= 0.25f; s3 *= 0.25f;

    float m = fmaxf(fmaxf(s0, s1), fmaxf(s2, s3));
    m = fmaxf(m, __shfl_xor(m, 32));
    float w0 = __expf(s0 - m), w1 = __expf(s1 - m);
    float w2 = __expf(s2 - m), w3 = __expf(s3 - m);
    float den = w0 + w1 + w2 + w3;
    den += __shfl_xor(den, 32);
    const float inv = 1.f / den;

    float ox = 0.f, oy = 0.f;
    ox = fmaf(w0, bf2f(vu0.x), ox); oy = fmaf(w0, bf2f(vu0.y), oy);
    ox = fmaf(w1, bf2f(vu1.x), ox); oy = fmaf(w1, bf2f(vu1.y), oy);
    ox = fmaf(w2, bf2f(vu2.x), ox); oy = fmaf(w2, bf2f(vu2.y), oy);
    ox = fmaf(w3, bf2f(vu3.x), ox); oy = fmaf(w3, bf2f(vu3.y), oy);
    ox = (ox + __shfl_xor(ox, 32)) * inv;
    oy = (oy + __shfl_xor(oy, 32)) * inv;

    if (lane < 32) {
        ushort2 o;
        o.x = f2bf(ox);
        o.y = f2bf(oy);
        *(ushort2*)(ao + (size_t)e * 64 + l32 * 2) = o;
    }
}

// ---------------------------------------------------------------------------
// Wo GEMM via MFMA + fused residual: out = ef_in + attn(bf16) @ Wo.
// ---------------------------------------------------------------------------
__global__ __launch_bounds__(256) void wo_mfma(
    const float* __restrict__ ef_in, const ushort* __restrict__ attn,
    const ushort* __restrict__ wofrag, float* __restrict__ efo)
{
    const int wave = threadIdx.x >> 6;
    const int lane = threadIdx.x & 63;
    const int r  = lane & 15;
    const int kg = lane >> 4;
    const int e0 = blockIdx.x * 64 + wave * 16;
    const int e  = e0 + r;
    const int ec = (e < NE) ? e : NE - 1;

    short8 af0 = *(const short8*)(attn + (size_t)ec * 64 + kg * 8);
    short8 af1 = *(const short8*)(attn + (size_t)ec * 64 + 32 + kg * 8);

    const char* wf = (const char*)wofrag + (size_t)lane * 16;
    f32x4 d0 = (f32x4)(0.f), d1 = (f32x4)(0.f), d2 = (f32x4)(0.f), d3 = (f32x4)(0.f);
    short8 g0 = *(const short8*)(wf + 0 * 1024);
    short8 g1 = *(const short8*)(wf + 1 * 1024);
    short8 g2 = *(const short8*)(wf + 2 * 1024);
    short8 g3 = *(const short8*)(wf + 3 * 1024);
    MFMA_B16(af0, g0, d0); MFMA_B16(af0, g1, d1);
    MFMA_B16(af0, g2, d2); MFMA_B16(af0, g3, d3);
    g0 = *(const short8*)(wf + 4 * 1024);
    g1 = *(const short8*)(wf + 5 * 1024);
    g2 = *(const short8*)(wf + 6 * 1024);
    g3 = *(const short8*)(wf + 7 * 1024);
    MFMA_B16(af1, g0, d0); MFMA_B16(af1, g1, d1);
    MFMA_B16(af1, g2, d2); MFMA_B16(af1, g3, d3);

    const int orow = e0 + kg * 4;
    #pragma unroll
    for (int t = 0; t < 4; ++t) {
        const f32x4 dd = (t == 0) ? d0 : (t == 1) ? d1 : (t == 2) ? d2 : d3;
        const int c = t * 16 + r;
        #pragma unroll
        for (int j = 0; j < 4; ++j) {
            int row = orow + j;
            if (row < NE) {
                size_t off = (size_t)row * 64 + c;
                efo[off] = dd[j] + ef_in[off];
            }
        }
    }
}

// ---------------------------------------------------------------------------
extern "C" void kernel_launch(void* const* d_in, const int* in_sizes, int n_in,
                              void* d_out, int out_size, void* d_ws, size_t ws_size,
                              hipStream_t stream)
{
    const float* nodef   = (const float*)d_in[0];
    const float* ef      = (const float*)d_in[1];
    const int*   eidx    = (const int*)d_in[2];   // [2,E]
    const int*   adj_src = (const int*)d_in[4];
    const float* l1Wq = (const float*)d_in[6];
    const float* l1Wk = (const float*)d_in[7];
    const float* l1Wv = (const float*)d_in[8];
    const float* l1Wo = (const float*)d_in[9];
    const float* l2Wq = (const float*)d_in[10];
    const float* l2Wk = (const float*)d_in[11];
    const float* l2Wv = (const float*)d_in[12];
    const float* l2Wo = (const float*)d_in[13];

    ushort* q   = (ushort*)d_ws;                 // [E,64] bf16
    ushort* k   = q   + (size_t)NE * 64;
    ushort* v   = k   + (size_t)NE * 64;
    ushort* ao  = v   + (size_t)NE * 64;
    ushort* wf1 = ao  + (size_t)NE * 64;         // 36864 ushorts each
    ushort* wf2 = wf1 + 36864;
    ushort* wo1 = wf2 + 36864;                   // 4096 each
    ushort* wo2 = wo1 + 4096;
    float* out = (float*)d_out;

    dim3 blk(256);
    const int gq = (NE + 31) / 32;    // 3125 (32 rows / block)
    const int ga = (NE + 3) / 4;      // 25000
    const int gw = (NE + 63) / 64;    // 1563

    prep_all<<<40, blk, 0, stream>>>(l1Wq, l1Wk, l1Wv, l1Wo,
                                     l2Wq, l2Wk, l2Wv, l2Wo,
                                     wf1, wf2, wo1, wo2);

    // ---- layer 1 ----
    qkv_mfma<<<gq, blk, 0, stream>>>(ef, nodef, eidx, wf1, q, k, v);
    attn_kernel<<<ga, blk, 0, stream>>>(q, k, v, adj_src, ao);
    wo_mfma<<<gw, blk, 0, stream>>>(ef, ao, wo1, out);
    // ---- layer 2 ----
    qkv_mfma<<<gq, blk, 0, stream>>>(out, nodef, eidx, wf2, q, k, v);
    attn_kernel<<<ga, blk, 0, stream>>>(q, k, v, adj_src, ao);
    wo_mfma<<<gw, blk, 0, stream>>>(out, ao, wo2, out);
}

// Round 12
// 153.148 us; speedup vs baseline: 1.2131x; 1.2131x over previous
//
#include <hip/hip_runtime.h>

#define NE 100000   // edges
#define NN 50000    // nodes
#define NT 1563     // ceil(NE/64) tiles
#define GRID_QKV 512

typedef short short8 __attribute__((ext_vector_type(8)));
typedef float f32x4 __attribute__((ext_vector_type(4)));
typedef unsigned short ushort;
typedef unsigned int uint;

__device__ inline ushort f2bf(float f) {
    unsigned int u = __float_as_uint(f);
    u += 0x7FFFu + ((u >> 16) & 1u);
    return (ushort)(u >> 16);
}
__device__ inline float bf2f(ushort u) {
    return __uint_as_float((unsigned int)u << 16);
}

__device__ inline short8 pack_bf8(float4 a, float4 b) {
    short8 r;
    r[0] = (short)f2bf(a.x); r[1] = (short)f2bf(a.y);
    r[2] = (short)f2bf(a.z); r[3] = (short)f2bf(a.w);
    r[4] = (short)f2bf(b.x); r[5] = (short)f2bf(b.y);
    r[6] = (short)f2bf(b.z); r[7] = (short)f2bf(b.w);
    return r;
}

// ---------------------------------------------------------------------------
// Prep: pack both layers' QKV (72 frags) + Wo (8 frags) into bf16 fragment
// order: wf[((s*12+t)*64+lane)*8+j] = W[k=32s+(lane>>4)*8+j][n=16t+(lane&15)]
// ---------------------------------------------------------------------------
__device__ inline void pack_qkv_slot(int slot, const float* Wq, const float* Wk,
                                     const float* Wv, ushort* wf)
{
    int lane = slot & 63;
    int st = slot >> 6;
    int s = st / 12, t = st % 12;
    int n = t * 16 + (lane & 15);
    int kb = s * 32 + (lane >> 4) * 8;
    const float* w = (n < 64) ? Wq : (n < 128) ? Wk : Wv;
    int nn = n & 63;
    #pragma unroll
    for (int j = 0; j < 8; ++j)
        wf[(size_t)slot * 8 + j] = f2bf(w[(size_t)(kb + j) * 64 + nn]);
}

__device__ inline void pack_wo_slot(int slot, const float* Wo, ushort* wf)
{
    int lane = slot & 63;
    int st = slot >> 6;
    int s = st / 4, t = st % 4;
    int n = t * 16 + (lane & 15);
    int kb = s * 32 + (lane >> 4) * 8;
    #pragma unroll
    for (int j = 0; j < 8; ++j)
        wf[(size_t)slot * 8 + j] = f2bf(Wo[(size_t)(kb + j) * 64 + n]);
}

__global__ __launch_bounds__(256) void prep_all(
    const float* __restrict__ l1Wq, const float* __restrict__ l1Wk,
    const float* __restrict__ l1Wv, const float* __restrict__ l1Wo,
    const float* __restrict__ l2Wq, const float* __restrict__ l2Wk,
    const float* __restrict__ l2Wv, const float* __restrict__ l2Wo,
    ushort* __restrict__ wf1, ushort* __restrict__ wf2,
    ushort* __restrict__ wo1, ushort* __restrict__ wo2)
{
    int idx = blockIdx.x * 256 + threadIdx.x;
    if (idx < 4608)            pack_qkv_slot(idx,         l1Wq, l1Wk, l1Wv, wf1);
    else if (idx < 9216)       pack_qkv_slot(idx - 4608,  l2Wq, l2Wk, l2Wv, wf2);
    else if (idx < 9728)       pack_wo_slot (idx - 9216,  l1Wo, wo1);
    else if (idx < 10240)      pack_wo_slot (idx - 9728,  l2Wo, wo2);
}

#define MFMA_B16(a, b, c) c = __builtin_amdgcn_mfma_f32_16x16x32_bf16(a, b, c, 0, 0, 0)
#define GLP const __attribute__((address_space(1))) uint*
#define LDP __attribute__((address_space(3))) uint*

// ---------------------------------------------------------------------------
// QKV GEMM — SMALL-CODE persistent kernel (I$-resident, loop-reused).
// 512 blocks (2/CU). Per block: stage ALL 72 W fragments (72 KB) into LDS
// once (looped global_load_lds), one barrier, then loop over ~3 tiles of
// 64 edge-rows. K-loop is a real loop (unroll 1): 1 gathered A-fragment
// pack + 12 ds_read_b128+MFMA per iteration. acc[12] stays in registers
// (inner t-loops unrolled; s/tile loops are not).
// ---------------------------------------------------------------------------
__global__ __launch_bounds__(256) void qkv_mfma(
    const float* __restrict__ ef, const float* __restrict__ nodef,
    const int* __restrict__ eidx, const ushort* __restrict__ wfrag,
    ushort* __restrict__ qo, ushort* __restrict__ ko, ushort* __restrict__ vo)
{
    __shared__ __align__(1024) char ldsb[72 * 1024];

    const int tid = threadIdx.x;
    const int l   = tid & 63;
    const int w   = tid >> 6;
    const int r   = l & 15;
    const int kg  = l >> 4;
    const int koff = kg * 8;

    // ---- stage all 72 B fragments once (wave w: frags w*18 .. w*18+17) ----
    #pragma unroll 1
    for (int i = 0; i < 18; ++i) {
        const int fr = w * 18 + i;
        __builtin_amdgcn_global_load_lds(
            (GLP)((const char*)wfrag + (size_t)fr * 1024 + (size_t)l * 16),
            (LDP)(ldsb + (size_t)fr * 1024 + (size_t)l * 16), 16, 0, 0);
    }
    __syncthreads();

    // ---- persistent tile loop ----
    #pragma unroll 1
    for (int tile = blockIdx.x; tile < NT; tile += GRID_QKV) {
        const int e0 = tile * 64 + w * 16;
        const int e  = e0 + r;
        const int ec = (e < NE) ? e : NE - 1;
        const float* rp0 = ef    + (size_t)ec * 64;
        const float* rp1 = nodef + (size_t)eidx[ec] * 64;
        const float* rp2 = nodef + (size_t)eidx[NE + ec] * 64;

        f32x4 acc[12];
        #pragma unroll
        for (int t = 0; t < 12; ++t) acc[t] = (f32x4)(0.f);

        #pragma unroll 1
        for (int s = 0; s < 6; ++s) {
            const float* bp = ((s < 2) ? rp0 : (s < 4) ? rp1 : rp2)
                              + (s & 1) * 32 + koff;
            short8 A = pack_bf8(*(const float4*)bp, *(const float4*)(bp + 4));
            const char* lb = ldsb + (size_t)s * 12288 + (size_t)l * 16;
            #pragma unroll
            for (int t = 0; t < 12; ++t) {
                short8 b = *(const short8*)(lb + (size_t)t * 1024);
                MFMA_B16(A, b, acc[t]);
            }
        }

        // ---- store: n-tile t -> col (t&3)*16+r of q/k/v; rows e0+kg*4+j ----
        const int orow = e0 + kg * 4;
        #pragma unroll
        for (int t = 0; t < 12; ++t) {
            ushort* dst = (t < 4) ? qo : (t < 8) ? ko : vo;
            ushort* dp  = dst + (t & 3) * 16 + r;
            #pragma unroll
            for (int j = 0; j < 4; ++j) {
                const int row = orow + j;
                if (row < NE) dp[(size_t)row * 64] = f2bf(acc[t][j]);
            }
        }
    }
}

// ---------------------------------------------------------------------------
// Attention: one wave per dst edge. lane = half*32 + h*8 + dd.
// ---------------------------------------------------------------------------
__global__ __launch_bounds__(256) void attn_kernel(
    const ushort* __restrict__ q, const ushort* __restrict__ kbuf,
    const ushort* __restrict__ vbuf, const int* __restrict__ adj_src,
    ushort* __restrict__ ao)
{
    const int wid  = (blockIdx.x * 256 + threadIdx.x) >> 6;
    const int lane = threadIdx.x & 63;
    if (wid >= NE) return;
    const int e    = wid;
    const int half = lane >> 5;
    const int l32  = lane & 31;

    const int4 nb = *(const int4*)(adj_src + e * 8 + half * 4);
    const int nbr0 = nb.x, nbr1 = nb.y, nbr2 = nb.z, nbr3 = nb.w;

    ushort2 qu = *(const ushort2*)(q + (size_t)e * 64 + l32 * 2);
    const float q0 = bf2f(qu.x), q1 = bf2f(qu.y);

    ushort2 ku0 = *(const ushort2*)(kbuf + (size_t)nbr0 * 64 + l32 * 2);
    ushort2 ku1 = *(const ushort2*)(kbuf + (size_t)nbr1 * 64 + l32 * 2);
    ushort2 ku2 = *(const ushort2*)(kbuf + (size_t)nbr2 * 64 + l32 * 2);
    ushort2 ku3 = *(const ushort2*)(kbuf + (size_t)nbr3 * 64 + l32 * 2);
    ushort2 vu0 = *(const ushort2*)(vbuf + (size_t)nbr0 * 64 + l32 * 2);
    ushort2 vu1 = *(const ushort2*)(vbuf + (size_t)nbr1 * 64 + l32 * 2);
    ushort2 vu2 = *(const ushort2*)(vbuf + (size_t)nbr2 * 64 + l32 * 2);
    ushort2 vu3 = *(const ushort2*)(vbuf + (size_t)nbr3 * 64 + l32 * 2);

    float s0 = q0 * bf2f(ku0.x) + q1 * bf2f(ku0.y);
    float s1 = q0 * bf2f(ku1.x) + q1 * bf2f(ku1.y);
    float s2 = q0 * bf2f(ku2.x) + q1 * bf2f(ku2.y);
    float s3 = q0 * bf2f(ku3.x) + q1 * bf2f(ku3.y);
    s0 += __shfl_xor(s0, 1); s0 += __shfl_xor(s0, 2); s0 += __shfl_xor(s0, 4);
    s1 += __shfl_xor(s1, 1); s1 += __shfl_xor(s1, 2); s1 += __shfl_xor(s1, 4);
    s2 += __shfl_xor(s2, 1); s2 += __shfl_xor(s2, 2); s2 += __shfl_xor(s2, 4);
    s3 += __shfl_xor(s3, 1); s3 += __shfl_xor(s3, 2); s3 += __shfl_xor(s3, 4);
    s0 *= 0.25f; s1 *= 0.25f; s2 *= 0.25f; s3 *= 0.25f;

    float m = fmaxf(fmaxf(s0, s1), fmaxf(s2, s3));
    m = fmaxf(m, __shfl_xor(m, 32));
    float w0 = __expf(s0 - m), w1 = __expf(s1 - m);
    float w2 = __expf(s2 - m), w3 = __expf(s3 - m);
    float den = w0 + w1 + w2 + w3;
    den += __shfl_xor(den, 32);
    const float inv = 1.f / den;

    float ox = 0.f, oy = 0.f;
    ox = fmaf(w0, bf2f(vu0.x), ox); oy = fmaf(w0, bf2f(vu0.y), oy);
    ox = fmaf(w1, bf2f(vu1.x), ox); oy = fmaf(w1, bf2f(vu1.y), oy);
    ox = fmaf(w2, bf2f(vu2.x), ox); oy = fmaf(w2, bf2f(vu2.y), oy);
    ox = fmaf(w3, bf2f(vu3.x), ox); oy = fmaf(w3, bf2f(vu3.y), oy);
    ox = (ox + __shfl_xor(ox, 32)) * inv;
    oy = (oy + __shfl_xor(oy, 32)) * inv;

    if (lane < 32) {
        ushort2 o;
        o.x = f2bf(ox);
        o.y = f2bf(oy);
        *(ushort2*)(ao + (size_t)e * 64 + l32 * 2) = o;
    }
}

// ---------------------------------------------------------------------------
// Wo GEMM via MFMA + fused residual: out = ef_in + attn(bf16) @ Wo.
// ---------------------------------------------------------------------------
__global__ __launch_bounds__(256) void wo_mfma(
    const float* __restrict__ ef_in, const ushort* __restrict__ attn,
    const ushort* __restrict__ wofrag, float* __restrict__ efo)
{
    const int wave = threadIdx.x >> 6;
    const int lane = threadIdx.x & 63;
    const int r  = lane & 15;
    const int kg = lane >> 4;
    const int e0 = blockIdx.x * 64 + wave * 16;
    const int e  = e0 + r;
    const int ec = (e < NE) ? e : NE - 1;

    short8 af0 = *(const short8*)(attn + (size_t)ec * 64 + kg * 8);
    short8 af1 = *(const short8*)(attn + (size_t)ec * 64 + 32 + kg * 8);

    const char* wf = (const char*)wofrag + (size_t)lane * 16;
    f32x4 d0 = (f32x4)(0.f), d1 = (f32x4)(0.f), d2 = (f32x4)(0.f), d3 = (f32x4)(0.f);
    short8 g0 = *(const short8*)(wf + 0 * 1024);
    short8 g1 = *(const short8*)(wf + 1 * 1024);
    short8 g2 = *(const short8*)(wf + 2 * 1024);
    short8 g3 = *(const short8*)(wf + 3 * 1024);
    MFMA_B16(af0, g0, d0); MFMA_B16(af0, g1, d1);
    MFMA_B16(af0, g2, d2); MFMA_B16(af0, g3, d3);
    g0 = *(const short8*)(wf + 4 * 1024);
    g1 = *(const short8*)(wf + 5 * 1024);
    g2 = *(const short8*)(wf + 6 * 1024);
    g3 = *(const short8*)(wf + 7 * 1024);
    MFMA_B16(af1, g0, d0); MFMA_B16(af1, g1, d1);
    MFMA_B16(af1, g2, d2); MFMA_B16(af1, g3, d3);

    const int orow = e0 + kg * 4;
    #pragma unroll
    for (int t = 0; t < 4; ++t) {
        const f32x4 dd = (t == 0) ? d0 : (t == 1) ? d1 : (t == 2) ? d2 : d3;
        const int c = t * 16 + r;
        #pragma unroll
        for (int j = 0; j < 4; ++j) {
            int row = orow + j;
            if (row < NE) {
                size_t off = (size_t)row * 64 + c;
                efo[off] = dd[j] + ef_in[off];
            }
        }
    }
}

// ---------------------------------------------------------------------------
extern "C" void kernel_launch(void* const* d_in, const int* in_sizes, int n_in,
                              void* d_out, int out_size, void* d_ws, size_t ws_size,
                              hipStream_t stream)
{
    const float* nodef   = (const float*)d_in[0];
    const float* ef      = (const float*)d_in[1];
    const int*   eidx    = (const int*)d_in[2];   // [2,E]
    const int*   adj_src = (const int*)d_in[4];
    const float* l1Wq = (const float*)d_in[6];
    const float* l1Wk = (const float*)d_in[7];
    const float* l1Wv = (const float*)d_in[8];
    const float* l1Wo = (const float*)d_in[9];
    const float* l2Wq = (const float*)d_in[10];
    const float* l2Wk = (const float*)d_in[11];
    const float* l2Wv = (const float*)d_in[12];
    const float* l2Wo = (const float*)d_in[13];

    ushort* q   = (ushort*)d_ws;                 // [E,64] bf16
    ushort* k   = q   + (size_t)NE * 64;
    ushort* v   = k   + (size_t)NE * 64;
    ushort* ao  = v   + (size_t)NE * 64;
    ushort* wf1 = ao  + (size_t)NE * 64;         // 36864 ushorts each
    ushort* wf2 = wf1 + 36864;
    ushort* wo1 = wf2 + 36864;                   // 4096 each
    ushort* wo2 = wo1 + 4096;
    float* out = (float*)d_out;

    dim3 blk(256);
    const int ga = (NE + 3) / 4;      // 25000
    const int gw = (NE + 63) / 64;    // 1563

    prep_all<<<40, blk, 0, stream>>>(l1Wq, l1Wk, l1Wv, l1Wo,
                                     l2Wq, l2Wk, l2Wv, l2Wo,
                                     wf1, wf2, wo1, wo2);

    // ---- layer 1 ----
    qkv_mfma<<<GRID_QKV, blk, 0, stream>>>(ef, nodef, eidx, wf1, q, k, v);
    attn_kernel<<<ga, blk, 0, stream>>>(q, k, v, adj_src, ao);
    wo_mfma<<<gw, blk, 0, stream>>>(ef, ao, wo1, out);
    // ---- layer 2 ----
    qkv_mfma<<<GRID_QKV, blk, 0, stream>>>(out, nodef, eidx, wf2, q, k, v);
    attn_kernel<<<ga, blk, 0, stream>>>(q, k, v, adj_src, ao);
    wo_mfma<<<gw, blk, 0, stream>>>(out, ao, wo2, out);
}